// Round 15
// baseline (31842.938 us; speedup 1.0000x reference)
//
#include <hip/hip_runtime.h>
#include <math.h>

#define D 128
#define NLAYER 16
#define V 17
#define L 1024
#define BOSX 16
#define NWG 256
#define NT 1024

struct P {
  const int* tokens;
  const float *emb, *pos, *ln1_s, *ln1_b, *wqkv, *bqkv, *wo, *bo;
  const float *ln2_s, *ln2_b, *w1, *b1, *w2, *b2, *lnf_s, *lnf_b, *hw, *hb;
  float *kc, *vc, *ll_;
  int *lat, *heal_row, *barc, *done, *heals_done, *prog;
  float *logits, *out_tok;
};

// ---- uncached (coherence-point) accessors ----
__device__ __forceinline__ void stUf(float* p, float v) {
  __hip_atomic_store(p, v, __ATOMIC_RELAXED, __HIP_MEMORY_SCOPE_SYSTEM);
}
__device__ __forceinline__ int ldUi(const int* p) {
  return __hip_atomic_load((int*)p, __ATOMIC_RELAXED, __HIP_MEMORY_SCOPE_SYSTEM);
}
__device__ __forceinline__ void stUi(int* p, int v) {
  __hip_atomic_store(p, v, __ATOMIC_RELAXED, __HIP_MEMORY_SCOPE_SYSTEM);
}

// ---- full barrier (phase A + transitions): wb/inv fence, relaxed spin ----
__device__ __forceinline__ void barFull(int* cnt, int& b) {
  asm volatile("s_waitcnt vmcnt(0)" ::: "memory");
  __syncthreads();
  if (threadIdx.x == 0) {
    __threadfence();
    __hip_atomic_fetch_add(cnt, 1, __ATOMIC_RELAXED, __HIP_MEMORY_SCOPE_AGENT);
    int tgt = (b + 1) * NWG;
    while (__hip_atomic_load(cnt, __ATOMIC_RELAXED, __HIP_MEMORY_SCOPE_AGENT) < tgt)
      __builtin_amdgcn_s_sleep(8);
    __threadfence();
  }
  b += 1;
  __syncthreads();
}

__device__ __forceinline__ float geluf(float a) {
  float cgv = 0.7978845608028654f * (a + 0.044715f * a * a * a);
  cgv = fminf(fmaxf(cgv, -15.f), 15.f);
  float e = __expf(2.f * cgv);
  return 0.5f * a * (1.f + (e - 1.f) / (e + 1.f));
}

// LayerNorm in[0..127]->out[0..127]; only t<128 compute
__device__ void lnorm(const float* __restrict__ s, const float* __restrict__ b,
                      const float* in, float* out, float* red) {
  int t = threadIdx.x;
  float v = (t < D) ? in[t] : 0.f;
  float sm = v;
#pragma unroll
  for (int o = 32; o; o >>= 1) sm += __shfl_xor(sm, o, 64);
  if (t < D && (t & 63) == 0) red[t >> 6] = sm;
  __syncthreads();
  float mean = (red[0] + red[1]) * (1.f / 128.f);
  float d = (t < D) ? (v - mean) : 0.f;
  float vs = d * d;
#pragma unroll
  for (int o = 32; o; o >>= 1) vs += __shfl_xor(vs, o, 64);
  if (t < D && (t & 63) == 0) red[2 + (t >> 6)] = vs;
  __syncthreads();
  float rstd = rsqrtf((red[2] + red[3]) * (1.f / 128.f) + 1e-5f);
  if (t < D) out[t] = d * rstd * s[t] + b[t];
  __syncthreads();
}

// QKV: 2 half-depth segs x 384 cols (scalar col-per-thread). q->LDS, K/V->global.
template <bool HEAL>
__device__ void qkvPub(const P& p, int l, int row, int split, const float* x,
                       float* qrow, float* padS) {
  int t = threadIdx.x;
  int half = (t >= 512) ? 1 : 0;
  int cq = half ? (t - 512) : t;
  if (cq < 384) {
    const float* w = p.wqkv + (size_t)l * D * 384 + cq;
    float a = 0.f;
    int d0 = half * 64;
#pragma unroll 16
    for (int d = d0; d < d0 + 64; ++d) a += x[d] * w[d * 384];
    padS[half * 384 + cq] = a;
  }
  __syncthreads();
  if (t < 384) {
    float a = padS[t] + padS[384 + t] + p.bqkv[l * 384 + t];
    float* kcl = p.kc + (size_t)l * L * D + (size_t)row * D;
    float* vcl = p.vc + (size_t)l * L * D + (size_t)row * D;
    if (t < 128) qrow[t] = a;
    else if (t < 256) { if (HEAL) stUf(&kcl[t - 128], a); else kcl[t - 128] = a; }
    else              { if (HEAL) stUf(&vcl[t - 256], a); else vcl[t - 256] = a; }
  }
  if (HEAL) {
    asm volatile("s_waitcnt vmcnt(0)" ::: "memory");
    __syncthreads();
    if (t == 0) {
      int* dl = p.done + l * L;
      if (row - 1 >= split)
        while (ldUi(&dl[row - 1]) < 1) __builtin_amdgcn_s_sleep(1);
      stUi(&dl[row], 1);
    }
    __syncthreads();
  } else {
    __syncthreads();
  }
}

// attention(l)+proj+res+LN2+FF1+FF2+res for one row; 1024 threads.
__device__ void attnProjFFN(const P& p, int row, int l,
                            float* hrow, const float* qrow,
                            float* oS, float* xnS, float* fS, float* padS, float* redS) {
  int t = threadIdx.x;
  const float* kcl = p.kc + (size_t)l * L * D;
  const float* vcl = p.vc + (size_t)l * L * D;
  // ---- attn: 16 heads x 64 lanes ----
  {
    int head = t >> 6, lane = t & 63;
    const float* qh = qrow + head * 8;
    float q0=qh[0],q1=qh[1],q2=qh[2],q3=qh[3],q4=qh[4],q5=qh[5],q6=qh[6],q7=qh[7];
    float sum = 0.f, a0=0,a1=0,a2=0,a3=0,a4=0,a5=0,a6=0,a7=0;
#pragma unroll 2
    for (int key = lane; key <= row; key += 64) {
      const float4* kp = (const float4*)(kcl + (size_t)key * D + head * 8);
      float4 k0 = kp[0], k1 = kp[1];
      float sc = q0*k0.x+q1*k0.y+q2*k0.z+q3*k0.w+q4*k1.x+q5*k1.y+q6*k1.z+q7*k1.w;
      float pr = __expf(sc * 0.35355339059327376f);
      const float4* vp = (const float4*)(vcl + (size_t)key * D + head * 8);
      float4 v0 = vp[0], v1 = vp[1];
      sum += pr;
      a0+=pr*v0.x; a1+=pr*v0.y; a2+=pr*v0.z; a3+=pr*v0.w;
      a4+=pr*v1.x; a5+=pr*v1.y; a6+=pr*v1.z; a7+=pr*v1.w;
    }
#pragma unroll
    for (int o = 1; o < 64; o <<= 1) {
      sum += __shfl_xor(sum, o, 64);
      a0 += __shfl_xor(a0, o, 64); a1 += __shfl_xor(a1, o, 64);
      a2 += __shfl_xor(a2, o, 64); a3 += __shfl_xor(a3, o, 64);
      a4 += __shfl_xor(a4, o, 64); a5 += __shfl_xor(a5, o, 64);
      a6 += __shfl_xor(a6, o, 64); a7 += __shfl_xor(a7, o, 64);
    }
    if (lane == 0) {
      float inv = 1.f / sum;
      oS[head*8+0]=a0*inv; oS[head*8+1]=a1*inv; oS[head*8+2]=a2*inv; oS[head*8+3]=a3*inv;
      oS[head*8+4]=a4*inv; oS[head*8+5]=a5*inv; oS[head*8+6]=a6*inv; oS[head*8+7]=a7*inv;
    }
  }
  __syncthreads();
  // ---- proj: 8 segs x 16 deep, 128 cols ----
  {
    int col = t & 127, seg = t >> 7;
    const float* wp = p.wo + (size_t)l * D * D + col;
    float acc = 0.f;
    int d0 = seg * 16;
#pragma unroll 16
    for (int d = d0; d < d0 + 16; ++d) acc += oS[d] * wp[d * D];
    padS[seg * 128 + col] = acc;
  }
  __syncthreads();
  if (t < D) {
    float a = 0.f;
#pragma unroll
    for (int s = 0; s < 8; ++s) a += padS[s * 128 + t];
    hrow[t] += a + p.bo[l * D + t];
  }
  __syncthreads();
  lnorm(p.ln2_s + l * D, p.ln2_b + l * D, hrow, xnS, redS);
  // ---- FF1: 2 segs x 64 deep, 512 cols ----
  {
    int half = (t >= 512) ? 1 : 0;
    int cq = half ? (t - 512) : t;
    const float* w1p = p.w1 + (size_t)l * D * 512 + cq;
    float acc = 0.f;
    int d0 = half * 64;
#pragma unroll 16
    for (int d = d0; d < d0 + 64; ++d) acc += xnS[d] * w1p[d * 512];
    padS[half * 512 + cq] = acc;
  }
  __syncthreads();
  if (t < 512) {
    fS[t] = geluf(padS[t] + padS[512 + t] + p.b1[l * 512 + t]);
  }
  __syncthreads();
  // ---- FF2: 8 segs x 64 deep, 128 cols ----
  {
    int col = t & 127, seg = t >> 7;
    const float* w2p = p.w2 + (size_t)l * 512 * D + col;
    float acc = 0.f;
    int d0 = seg * 64;
#pragma unroll 16
    for (int d = d0; d < d0 + 64; ++d) acc += fS[d] * w2p[d * D];
    padS[seg * 128 + col] = acc;
  }
  __syncthreads();
  if (t < D) {
    float a = 0.f;
#pragma unroll
    for (int s = 0; s < 8; ++s) a += padS[s * 128 + t];
    hrow[t] += a + p.b2[l * D + t];
  }
  __syncthreads();
}

// LNf + head for one row; logits -> global (+ oS LDS for argmax)
template <bool HEAL>
__device__ void headRow(const P& p, int row, float* hrow,
                        float* xnS, float* redS, float* padS, float* oS) {
  lnorm(p.lnf_s, p.lnf_b, hrow, xnS, redS);
  int t = threadIdx.x;
  if (t < V * 8) {
    int col = t >> 3, seg = t & 7;
    float acc = 0.f;
    int d0 = seg * 16;
#pragma unroll
    for (int d = d0; d < d0 + 16; ++d) acc += xnS[d] * p.hw[d * V + col];
    padS[t] = acc;
  }
  __syncthreads();
  if (t < V) {
    float a = padS[t*8]+padS[t*8+1]+padS[t*8+2]+padS[t*8+3]
            + padS[t*8+4]+padS[t*8+5]+padS[t*8+6]+padS[t*8+7] + p.hb[t];
    oS[t] = a;
    if (HEAL) stUf(&p.logits[row * V + t], a);
    else      p.logits[row * V + t] = a;
  }
  __syncthreads();
}

// ---- init: lat + flags, all uncached ----
__global__ void kInit(const int* __restrict__ tokens, int* __restrict__ lat,
                      int* __restrict__ barc, int* __restrict__ done,
                      int* __restrict__ hd) {
  int i = blockIdx.x * blockDim.x + threadIdx.x;
  if (i == 0) stUi(lat, BOSX);
  if (i < L) stUi(lat + i + 1, tokens[i]);
  if (i < 64) stUi(barc + i, 0);
  if (i < 16) stUi(hd + i, 0);   // heals_done[0..7], prog at hd+8
  if (i < NLAYER * L) stUi(done + i, 0);
}

__global__ void __launch_bounds__(NT, 1) kMega(P p) {
  __shared__ float hS[4][D];
  __shared__ float qS[4][D];
  __shared__ float xnS[D];
  __shared__ float oS[D];
  __shared__ float fS[512];
  __shared__ float padS[1024];
  __shared__ float redS[16];
  __shared__ float sortS[L];
  __shared__ int cntS[NT + 1];
  int wg = blockIdx.x, t = threadIdx.x;
  int b = 0;
  int* cnt = p.barc;

  // ================= PHASE A: full pass, 4 rows/WG, cached =================
  for (int i = 0; i < 4; ++i) {
    int row = wg + i * NWG;
    int tok = p.lat[row];
    if (t < D) hS[i][t] = p.emb[tok * D + t] + p.pos[row * D + t];
    __syncthreads();
    lnorm(p.ln1_s, p.ln1_b, hS[i], xnS, redS);
    qkvPub<false>(p, 0, row, 0, xnS, qS[i], padS);
  }
  barFull(cnt, b);
  for (int l = 0; l < NLAYER; ++l) {
    for (int i = 0; i < 4; ++i) {
      int row = wg + i * NWG;
      attnProjFFN(p, row, l, hS[i], qS[i], oS, xnS, fS, padS, redS);
      if (l < NLAYER - 1) {
        lnorm(p.ln1_s + (l+1)*D, p.ln1_b + (l+1)*D, hS[i], xnS, redS);
        qkvPub<false>(p, l + 1, row, 0, xnS, qS[i], padS);
      } else {
        headRow<false>(p, row, hS[i], xnS, redS, padS, oS);
      }
    }
    barFull(cnt, b);
  }

  // ================= log-likelihoods =================
  {
    int gid = wg * NT + t;
    if (gid < L) {
      float r[V];
#pragma unroll
      for (int v = 0; v < V; ++v) r[v] = p.logits[gid * V + v];
      float m = r[0];
#pragma unroll
      for (int v = 1; v < V; ++v) m = fmaxf(m, r[v]);
      float s = 0.f;
#pragma unroll
      for (int v = 0; v < V; ++v) s += expf(r[v] - m);
      p.ll_[gid] = r[p.lat[gid + 1]] - (m + logf(s));
    }
  }
  barFull(cnt, b);

  // ================= sort + quantile + heal list (WG 0) =================
  if (wg == 0) {
    sortS[t] = p.ll_[t];
    __syncthreads();
    for (int ksz = 2; ksz <= L; ksz <<= 1) {
      for (int j = ksz >> 1; j; j >>= 1) {
        int pr = t ^ j;
        if (pr > t) {
          bool up = ((t & ksz) == 0);
          float a = sortS[t], bb = sortS[pr];
          if ((a > bb) == up) { sortS[t] = bb; sortS[pr] = a; }
        }
        __syncthreads();
      }
    }
    if (t == 0) {
      double frac = 0.03 * 1023.0 - 30.0;  // 0.69
      redS[0] = (float)((double)sortS[30] + frac * ((double)sortS[31] - (double)sortS[30]));
    }
    __syncthreads();
    float val = redS[0];
    int cc = (p.ll_[t] < val) ? 1 : 0;
    cntS[t] = cc;
    __syncthreads();
    if (t == 0) {
      int run = 0;
      for (int i = 0; i < NT; ++i) { int c2 = cntS[i]; cntS[i] = run; run += c2; }
      cntS[NT] = run;
    }
    __syncthreads();
    if (cc && cntS[t] < 31) p.heal_row[cntS[t]] = t;
    __syncthreads();
    if (t == 0) {
      int c = cntS[NT]; if (c > 31) c = 31;
      p.heal_row[31] = c;
      stUi(p.heals_done, 1);
      if (c > 0) {
        int r0 = p.heal_row[0];
        int best = 0; float bv = p.logits[r0 * V];
        for (int v = 1; v < BOSX; ++v) {
          float x = p.logits[r0 * V + v];
          if (x > bv) { bv = x; best = v; }
        }
        stUi(&p.lat[r0 + 1], best);
      }
    }
  }
  barFull(cnt, b);  // inv: drops all phase-A K/V lines from every L2/L1

  // ===== HEAL: row pipeline + warm-while-waiting, distance-aware backoff ====
  int c = p.heal_row[31];
  int split = (c > 0) ? (p.heal_row[0] + 1) : L;
  for (int r = split + wg; r < L; r += NWG) {
    int nh = 0, hk = -1;
    bool leadRow = false;  // r == heal_row[j]+1 for some j: lat[r] changes
    for (int j = 0; j < c; ++j) {
      nh += (p.heal_row[j] < r) ? 1 : 0;
      if (j >= 1 && p.heal_row[j] == r) hk = j;
      if (p.heal_row[j] == r - 1) leadRow = true;
    }
    // --- wait for chunk turn: warm L2 + distance-aware poll backoff ---
    {
      int pfi = (wg * 11) % 224;
      for (;;) {
        if (t == 0) { cntS[0] = ldUi(p.heals_done); cntS[1] = ldUi(p.prog); }
        __syncthreads();
        int hd = cntS[0];
        int pl = (cntS[1] + 1) & 15;
        if (hd >= nh) break;
        int dist = nh - hd;
        if (leadRow && dist == 1) {
          // critical-path wake: tight poll, no warm traffic
          __builtin_amdgcn_s_sleep(1);
          __syncthreads();
          continue;
        }
        // warm next layer's weights + finalized K/V rows (t<512 only)
        int R = p.heal_row[hd - 1];  // rows <= R are final at every layer
        float sink = 0.f;
        if (t < 512) {
#pragma unroll
          for (int j2 = 0; j2 < 6; ++j2) {
            int ch = pfi + j2; if (ch >= 224) ch -= 224;
            const float* basep = nullptr;
            if (ch < 24)      basep = p.wqkv + (size_t)pl * D * 384 + ch * 2048;
            else if (ch < 32) basep = p.wo   + (size_t)pl * D * D   + (ch - 24) * 2048;
            else if (ch < 64) basep = p.w1   + (size_t)pl * D * 512 + (ch - 32) * 2048;
            else if (ch < 96) basep = p.w2   + (size_t)pl * 512 * D + (ch - 64) * 2048;
            else {
              int kvch = ch - 96;          // 0..127: 64 K-blocks + 64 V-blocks
              int blk = (kvch & 63) * 16;  // 16 rows x 128 floats
              if (blk + 15 <= R)
                basep = (kvch < 64 ? p.kc : p.vc) + (size_t)pl * L * D + (size_t)blk * D;
            }
            if (basep) {
              float4 v = *(const float4*)(basep + t * 4);
              sink += v.x + v.y + v.z + v.w;
            }
          }
        }
        asm volatile("" :: "v"(sink));  // keep warm loads live (no DCE)
        pfi += 6; if (pfi >= 224) pfi -= 224;
        // graded backoff: far-away WGs poll rarely (coherence-point relief)
        if (dist >= 4) {
          __builtin_amdgcn_s_sleep(127); __builtin_amdgcn_s_sleep(127);
          __builtin_amdgcn_s_sleep(127); __builtin_amdgcn_s_sleep(127);
        } else if (dist >= 2) {
          __builtin_amdgcn_s_sleep(127);
        } else {
          __builtin_amdgcn_s_sleep(32);
        }
        __syncthreads();  // all waves done reading cntS before next poll-write
      }
      if (t == 0) cntS[0] = ldUi(&p.lat[r]);
      __syncthreads();
    }
    int tok = cntS[0];
    if (t < D) hS[0][t] = p.emb[tok * D + t] + p.pos[r * D + t];
    __syncthreads();
    lnorm(p.ln1_s, p.ln1_b, hS[0], xnS, redS);
    qkvPub<true>(p, 0, r, split, xnS, qS[0], padS);
    for (int l = 0; l < NLAYER; ++l) {
      if (leadRow && t == 0) stUi(p.prog, l);  // wave leader publishes layer
      attnProjFFN(p, r, l, hS[0], qS[0], oS, xnS, fS, padS, redS);
      if (l < NLAYER - 1) {
        lnorm(p.ln1_s + (l+1)*D, p.ln1_b + (l+1)*D, hS[0], xnS, redS);
        qkvPub<true>(p, l + 1, r, split, xnS, qS[0], padS);
      } else {
        headRow<true>(p, r, hS[0], xnS, redS, padS, oS);
      }
    }
    if (hk >= 0 && t == 0) {
      int best = 0; float bv = oS[0];
      for (int v = 1; v < BOSX; ++v)
        if (oS[v] > bv) { bv = oS[v]; best = v; }
      stUi(&p.lat[r + 1], best);
      asm volatile("s_waitcnt vmcnt(0)" ::: "memory");
      stUi(p.heals_done, hk + 1);
    }
  }

  barFull(cnt, b);

  // ================= tokens out =================
  {
    int gid = wg * NT + t;
    if (gid < L) p.out_tok[gid] = (float)ldUi(&p.lat[gid + 1]);
  }
}

extern "C" void kernel_launch(void* const* d_in, const int* in_sizes, int n_in,
                              void* d_out, int out_size, void* d_ws, size_t ws_size,
                              hipStream_t stream) {
  P prm;
  prm.tokens = (const int*)d_in[0];
  prm.emb    = (const float*)d_in[1];
  prm.pos    = (const float*)d_in[2];
  prm.ln1_s  = (const float*)d_in[3];
  prm.ln1_b  = (const float*)d_in[4];
  prm.wqkv   = (const float*)d_in[5];
  prm.bqkv   = (const float*)d_in[6];
  prm.wo     = (const float*)d_in[7];
  prm.bo     = (const float*)d_in[8];
  prm.ln2_s  = (const float*)d_in[9];
  prm.ln2_b  = (const float*)d_in[10];
  prm.w1     = (const float*)d_in[11];
  prm.b1     = (const float*)d_in[12];
  prm.w2     = (const float*)d_in[13];
  prm.b2     = (const float*)d_in[14];
  prm.lnf_s  = (const float*)d_in[15];
  prm.lnf_b  = (const float*)d_in[16];
  prm.hw     = (const float*)d_in[17];
  prm.hb     = (const float*)d_in[18];

  float* ws = (float*)d_ws;
  prm.kc   = ws;                            // NLAYER*L*D
  prm.vc   = prm.kc + (size_t)NLAYER*L*D;   // NLAYER*L*D
  prm.ll_  = prm.vc + (size_t)NLAYER*L*D;   // L
  prm.lat        = (int*)(prm.ll_ + L);     // 1025 (pad 1032)
  prm.heal_row   = prm.lat + 1032;          // 32 ([31] = count)
  prm.barc       = prm.heal_row + 32;       // 64
  prm.done       = prm.barc + 64;           // NLAYER*L
  prm.heals_done = prm.done + NLAYER * L;   // 16 (prog = +8, zeroed by kInit)
  prm.prog       = prm.heals_done + 8;

  prm.logits  = (float*)d_out;              // L*V
  prm.out_tok = prm.logits + L * V;         // L

  kInit<<<64, 256, 0, stream>>>(prm.tokens, prm.lat, prm.barc, prm.done, prm.heals_done);

  void* args[] = { &prm };
  (void)hipLaunchCooperativeKernel((const void*)kMega, dim3(NWG), dim3(NT), args, 0, stream);
}

// Round 16
// 17513.231 us; speedup vs baseline: 1.8182x; 1.8182x over previous
//
#include <hip/hip_runtime.h>
#include <math.h>

#define D 128
#define NLAYER 16
#define V 17
#define L 1024
#define BOSX 16
#define NWG 256
#define NT 512

struct P {
  const int* tokens;
  const float *emb, *pos, *ln1_s, *ln1_b, *wqkv, *bqkv, *wo, *bo;
  const float *ln2_s, *ln2_b, *w1, *b1, *w2, *b2, *lnf_s, *lnf_b, *hw, *hb;
  float *kc, *vc, *ll_;
  int *lat, *heal_row, *barc, *done, *heals_done, *prog;
  float *logits, *out_tok;
};

// ---- uncached (coherence-point) accessors ----
__device__ __forceinline__ void stUf(float* p, float v) {
  __hip_atomic_store(p, v, __ATOMIC_RELAXED, __HIP_MEMORY_SCOPE_SYSTEM);
}
__device__ __forceinline__ int ldUi(const int* p) {
  return __hip_atomic_load((int*)p, __ATOMIC_RELAXED, __HIP_MEMORY_SCOPE_SYSTEM);
}
__device__ __forceinline__ void stUi(int* p, int v) {
  __hip_atomic_store(p, v, __ATOMIC_RELAXED, __HIP_MEMORY_SCOPE_SYSTEM);
}

// ---- full barrier (phase A + transitions): wb/inv fence, relaxed spin ----
__device__ __forceinline__ void barFull(int* cnt, int& b) {
  asm volatile("s_waitcnt vmcnt(0)" ::: "memory");
  __syncthreads();
  if (threadIdx.x == 0) {
    __threadfence();
    __hip_atomic_fetch_add(cnt, 1, __ATOMIC_RELAXED, __HIP_MEMORY_SCOPE_AGENT);
    int tgt = (b + 1) * NWG;
    while (__hip_atomic_load(cnt, __ATOMIC_RELAXED, __HIP_MEMORY_SCOPE_AGENT) < tgt)
      __builtin_amdgcn_s_sleep(8);
    __threadfence();
  }
  b += 1;
  __syncthreads();
}

__device__ __forceinline__ float geluf(float a) {
  float cgv = 0.7978845608028654f * (a + 0.044715f * a * a * a);
  cgv = fminf(fmaxf(cgv, -15.f), 15.f);
  float e = __expf(2.f * cgv);
  return 0.5f * a * (1.f + (e - 1.f) / (e + 1.f));
}

// LayerNorm in[0..127]->out[0..127]; 512 threads (t<128 compute)
__device__ void lnorm(const float* __restrict__ s, const float* __restrict__ b,
                      const float* in, float* out, float* red) {
  int t = threadIdx.x;
  float v = (t < D) ? in[t] : 0.f;
  float sm = v;
#pragma unroll
  for (int o = 32; o; o >>= 1) sm += __shfl_xor(sm, o, 64);
  if (t < D && (t & 63) == 0) red[t >> 6] = sm;
  __syncthreads();
  float mean = (red[0] + red[1]) * (1.f / 128.f);
  float d = (t < D) ? (v - mean) : 0.f;
  float vs = d * d;
#pragma unroll
  for (int o = 32; o; o >>= 1) vs += __shfl_xor(vs, o, 64);
  if (t < D && (t & 63) == 0) red[2 + (t >> 6)] = vs;
  __syncthreads();
  float rstd = rsqrtf((red[2] + red[3]) * (1.f / 128.f) + 1e-5f);
  if (t < D) out[t] = d * rstd * s[t] + b[t];
  __syncthreads();
}

// QKV for one row: q->LDS, K/V->global (uncached + done-chain when HEAL)
template <bool HEAL>
__device__ void qkvPub(const P& p, int l, int row, int split, const float* x, float* qrow) {
  int t = threadIdx.x;
  if (t < 384) {
    const float* w = p.wqkv + (size_t)l * D * 384 + t;
    float a = 0.f;
#pragma unroll 16
    for (int d = 0; d < D; ++d) a += x[d] * w[d * 384];
    a += p.bqkv[l * 384 + t];
    float* kcl = p.kc + (size_t)l * L * D + (size_t)row * D;
    float* vcl = p.vc + (size_t)l * L * D + (size_t)row * D;
    if (t < 128) qrow[t] = a;
    else if (t < 256) { if (HEAL) stUf(&kcl[t - 128], a); else kcl[t - 128] = a; }
    else              { if (HEAL) stUf(&vcl[t - 256], a); else vcl[t - 256] = a; }
  }
  if (HEAL) {
    asm volatile("s_waitcnt vmcnt(0)" ::: "memory");
    __syncthreads();
    if (t == 0) {
      int* dl = p.done + l * L;
      if (row - 1 >= split)
        while (ldUi(&dl[row - 1]) < 1) __builtin_amdgcn_s_sleep(1);
      stUi(&dl[row], 1);
    }
    __syncthreads();
  } else {
    __syncthreads();
  }
}

// attention(l)+proj+res+LN2+FF1+FF2+res for one row (h in LDS). K/V reads cached.
__device__ void attnProjFFN(const P& p, int row, int l,
                            float* hrow, const float* qrow,
                            float* oS, float* xnS, float* fS, float* padS, float* redS) {
  int t = threadIdx.x;
  const float* kcl = p.kc + (size_t)l * L * D;
  const float* vcl = p.vc + (size_t)l * L * D;
  int head = t >> 5, lane = t & 31;
  const float* qh = qrow + head * 8;
  float q0=qh[0],q1=qh[1],q2=qh[2],q3=qh[3],q4=qh[4],q5=qh[5],q6=qh[6],q7=qh[7];
  float sum = 0.f, a0=0,a1=0,a2=0,a3=0,a4=0,a5=0,a6=0,a7=0;
#pragma unroll 2
  for (int key = lane; key <= row; key += 32) {
    const float4* kp = (const float4*)(kcl + (size_t)key * D + head * 8);
    float4 k0 = kp[0], k1 = kp[1];
    float sc = q0*k0.x+q1*k0.y+q2*k0.z+q3*k0.w+q4*k1.x+q5*k1.y+q6*k1.z+q7*k1.w;
    float pr = __expf(sc * 0.35355339059327376f);
    const float4* vp = (const float4*)(vcl + (size_t)key * D + head * 8);
    float4 v0 = vp[0], v1 = vp[1];
    sum += pr;
    a0+=pr*v0.x; a1+=pr*v0.y; a2+=pr*v0.z; a3+=pr*v0.w;
    a4+=pr*v1.x; a5+=pr*v1.y; a6+=pr*v1.z; a7+=pr*v1.w;
  }
#pragma unroll
  for (int o = 1; o < 32; o <<= 1) {
    sum += __shfl_xor(sum, o, 32);
    a0 += __shfl_xor(a0, o, 32); a1 += __shfl_xor(a1, o, 32);
    a2 += __shfl_xor(a2, o, 32); a3 += __shfl_xor(a3, o, 32);
    a4 += __shfl_xor(a4, o, 32); a5 += __shfl_xor(a5, o, 32);
    a6 += __shfl_xor(a6, o, 32); a7 += __shfl_xor(a7, o, 32);
  }
  if (lane == 0) {
    float inv = 1.f / sum;
    oS[head*8+0]=a0*inv; oS[head*8+1]=a1*inv; oS[head*8+2]=a2*inv; oS[head*8+3]=a3*inv;
    oS[head*8+4]=a4*inv; oS[head*8+5]=a5*inv; oS[head*8+6]=a6*inv; oS[head*8+7]=a7*inv;
  }
  __syncthreads();
  // ---- proj: 4 segs x 32 deep ----
  {
    int col = t & 127, seg = t >> 7;
    const float* wp = p.wo + (size_t)l * D * D + col;
    float acc = 0.f;
    int d0 = seg * 32;
#pragma unroll 8
    for (int d = d0; d < d0 + 32; ++d) acc += oS[d] * wp[d * D];
    padS[t] = acc;
  }
  __syncthreads();
  if (t < D) hrow[t] += padS[t] + padS[t+128] + padS[t+256] + padS[t+384] + p.bo[l * D + t];
  __syncthreads();
  lnorm(p.ln2_s + l * D, p.ln2_b + l * D, hrow, xnS, redS);
  // ---- FF1: col per thread ----
  {
    const float* w1p = p.w1 + (size_t)l * D * 512 + t;
    float acc = 0.f;
#pragma unroll 16
    for (int d = 0; d < D; ++d) acc += xnS[d] * w1p[d * 512];
    fS[t] = geluf(acc + p.b1[l * 512 + t]);
  }
  __syncthreads();
  // ---- FF2: 4 segs x 128 deep ----
  {
    int col = t & 127, seg = t >> 7;
    const float* w2p = p.w2 + (size_t)l * 512 * D + col;
    float acc = 0.f;
    int d0 = seg * 128;
#pragma unroll 16
    for (int d = d0; d < d0 + 128; ++d) acc += fS[d] * w2p[d * D];
    padS[t] = acc;
  }
  __syncthreads();
  if (t < D) hrow[t] += padS[t] + padS[t+128] + padS[t+256] + padS[t+384] + p.b2[l * D + t];
  __syncthreads();
}

// LNf + head for one row; logits -> global (+ oS LDS for argmax)
template <bool HEAL>
__device__ void headRow(const P& p, int row, float* hrow,
                        float* xnS, float* redS, float* padS, float* oS) {
  lnorm(p.lnf_s, p.lnf_b, hrow, xnS, redS);
  int t = threadIdx.x;
  if (t < V * 8) {
    int col = t >> 3, seg = t & 7;
    float acc = 0.f;
    int d0 = seg * 16;
#pragma unroll
    for (int d = d0; d < d0 + 16; ++d) acc += xnS[d] * p.hw[d * V + col];
    padS[t] = acc;
  }
  __syncthreads();
  if (t < V) {
    float a = padS[t*8]+padS[t*8+1]+padS[t*8+2]+padS[t*8+3]
            + padS[t*8+4]+padS[t*8+5]+padS[t*8+6]+padS[t*8+7] + p.hb[t];
    oS[t] = a;
    if (HEAL) stUf(&p.logits[row * V + t], a);
    else      p.logits[row * V + t] = a;
  }
  __syncthreads();
}

// ---- init: lat + flags, all uncached ----
__global__ void kInit(const int* __restrict__ tokens, int* __restrict__ lat,
                      int* __restrict__ barc, int* __restrict__ done,
                      int* __restrict__ hd) {
  int i = blockIdx.x * blockDim.x + threadIdx.x;
  if (i == 0) stUi(lat, BOSX);
  if (i < L) stUi(lat + i + 1, tokens[i]);
  if (i < 64) stUi(barc + i, 0);
  if (i < 16) stUi(hd + i, 0);   // heals_done[0..7], prog at hd+8
  if (i < NLAYER * L) stUi(done + i, 0);
}

__global__ void __launch_bounds__(NT, 1) kMega(P p) {
  __shared__ float hS[4][D];
  __shared__ float qS[4][D];
  __shared__ float xnS[D];
  __shared__ float oS[D];
  __shared__ float fS[512];
  __shared__ float padS[512];
  __shared__ float redS[16];
  __shared__ float sortS[L];
  __shared__ int cntS[NT + 1];
  int wg = blockIdx.x, t = threadIdx.x;
  int b = 0;
  int* cnt = p.barc;

  // ================= PHASE A: full pass, 4 rows/WG, cached =================
  for (int i = 0; i < 4; ++i) {
    int row = wg + i * NWG;
    int tok = p.lat[row];
    if (t < D) hS[i][t] = p.emb[tok * D + t] + p.pos[row * D + t];
    __syncthreads();
    lnorm(p.ln1_s, p.ln1_b, hS[i], xnS, redS);
    qkvPub<false>(p, 0, row, 0, xnS, qS[i]);
  }
  barFull(cnt, b);
  for (int l = 0; l < NLAYER; ++l) {
    for (int i = 0; i < 4; ++i) {
      int row = wg + i * NWG;
      attnProjFFN(p, row, l, hS[i], qS[i], oS, xnS, fS, padS, redS);
      if (l < NLAYER - 1) {
        lnorm(p.ln1_s + (l+1)*D, p.ln1_b + (l+1)*D, hS[i], xnS, redS);
        qkvPub<false>(p, l + 1, row, 0, xnS, qS[i]);
      } else {
        headRow<false>(p, row, hS[i], xnS, redS, padS, oS);
      }
    }
    barFull(cnt, b);
  }

  // ================= log-likelihoods =================
  {
    int gid = wg * NT + t;
    if (gid < L) {
      float r[V];
#pragma unroll
      for (int v = 0; v < V; ++v) r[v] = p.logits[gid * V + v];
      float m = r[0];
#pragma unroll
      for (int v = 1; v < V; ++v) m = fmaxf(m, r[v]);
      float s = 0.f;
#pragma unroll
      for (int v = 0; v < V; ++v) s += expf(r[v] - m);
      p.ll_[gid] = r[p.lat[gid + 1]] - (m + logf(s));
    }
  }
  barFull(cnt, b);

  // ================= sort + quantile + heal list (WG 0) =================
  if (wg == 0) {
    for (int i = t; i < L; i += NT) sortS[i] = p.ll_[i];
    __syncthreads();
    for (int ksz = 2; ksz <= L; ksz <<= 1) {
      for (int j = ksz >> 1; j; j >>= 1) {
        for (int i = t; i < L; i += NT) {
          int l2 = i ^ j;
          if (l2 > i) {
            bool up = ((i & ksz) == 0);
            float a = sortS[i], bb = sortS[l2];
            if ((a > bb) == up) { sortS[i] = bb; sortS[l2] = a; }
          }
        }
        __syncthreads();
      }
    }
    if (t == 0) {
      double frac = 0.03 * 1023.0 - 30.0;  // 0.69
      redS[0] = (float)((double)sortS[30] + frac * ((double)sortS[31] - (double)sortS[30]));
    }
    __syncthreads();
    float val = redS[0];
    float lv0 = p.ll_[t * 2], lv1 = p.ll_[t * 2 + 1];
    int loc[2], cc = 0;
    if (lv0 < val) loc[cc++] = t * 2;
    if (lv1 < val) loc[cc++] = t * 2 + 1;
    cntS[t] = cc;
    __syncthreads();
    if (t == 0) {
      int run = 0;
      for (int i = 0; i < NT; ++i) { int c2 = cntS[i]; cntS[i] = run; run += c2; }
      cntS[NT] = run;
    }
    __syncthreads();
    int base = cntS[t];
    for (int j = 0; j < cc; ++j)
      if (base + j < 31) p.heal_row[base + j] = loc[j];
    __syncthreads();
    if (t == 0) {
      int c = cntS[NT]; if (c > 31) c = 31;
      p.heal_row[31] = c;
      stUi(p.heals_done, 1);
      if (c > 0) {
        int r0 = p.heal_row[0];
        int best = 0; float bv = p.logits[r0 * V];
        for (int v = 1; v < BOSX; ++v) {
          float x = p.logits[r0 * V + v];
          if (x > bv) { bv = x; best = v; }
        }
        stUi(&p.lat[r0 + 1], best);
      }
    }
  }
  barFull(cnt, b);  // inv: drops all phase-A K/V lines from every L2/L1

  // ===== HEAL: continuous wavefront. Non-lead rows flow on the done-chain; =====
  // ===== only lead rows (token changed by a heal) gate on heals_done.      =====
  int c = p.heal_row[31];
  int split = (c > 0) ? (p.heal_row[0] + 1) : L;
  for (int r = split + wg; r < L; r += NWG) {
    int nh = 0, hk = -1;
    bool leadRow = false;  // r == heal_row[j]+1 for some j: lat[r] changes
    for (int j = 0; j < c; ++j) {
      nh += (p.heal_row[j] < r) ? 1 : 0;
      if (j >= 1 && p.heal_row[j] == r) hk = j;
      if (p.heal_row[j] == r - 1) leadRow = true;
    }
    // gate: lead rows need ALL prior heals (their token is heal output);
    // non-lead rows only coarse-gate to within 2 heals (done-chain does the rest)
    int gate = leadRow ? nh : (nh - 2);
    // --- wait: warm L2 + distance-aware poll backoff ---
    {
      int pfi = (wg * 11) % 224;
      for (;;) {
        if (t == 0) { cntS[0] = ldUi(p.heals_done); cntS[1] = ldUi(p.prog); }
        __syncthreads();
        int hd = cntS[0];
        int pl = (cntS[1] + 1) & 15;
        if (hd >= gate) break;
        int dist = gate - hd;
        if (leadRow && dist == 1) {
          // critical-path wake: tight poll, no warm traffic
          __builtin_amdgcn_s_sleep(1);
          __syncthreads();
          continue;
        }
        // warm next layer's weights + finalized K/V rows
        int R = p.heal_row[hd - 1];  // rows <= R are final at every layer
        float sink = 0.f;
#pragma unroll
        for (int j2 = 0; j2 < 6; ++j2) {
          int ch = pfi + j2; if (ch >= 224) ch -= 224;
          const float* basep = nullptr;
          if (ch < 24)      basep = p.wqkv + (size_t)pl * D * 384 + ch * 2048;
          else if (ch < 32) basep = p.wo   + (size_t)pl * D * D   + (ch - 24) * 2048;
          else if (ch < 64) basep = p.w1   + (size_t)pl * D * 512 + (ch - 32) * 2048;
          else if (ch < 96) basep = p.w2   + (size_t)pl * 512 * D + (ch - 64) * 2048;
          else {
            int kvch = ch - 96;          // 0..127: 64 K-blocks + 64 V-blocks
            int blk = (kvch & 63) * 16;  // 16 rows x 128 floats
            if (blk + 15 <= R)
              basep = (kvch < 64 ? p.kc : p.vc) + (size_t)pl * L * D + (size_t)blk * D;
          }
          if (basep) {
            float4 v = *(const float4*)(basep + t * 4);
            sink += v.x + v.y + v.z + v.w;
          }
        }
        asm volatile("" :: "v"(sink));  // keep warm loads live (no DCE)
        pfi += 6; if (pfi >= 224) pfi -= 224;
        // graded backoff: far-away WGs poll rarely (coherence-point relief)
        if (dist >= 4) {
          __builtin_amdgcn_s_sleep(127); __builtin_amdgcn_s_sleep(127);
          __builtin_amdgcn_s_sleep(127); __builtin_amdgcn_s_sleep(127);
        } else if (dist >= 2) {
          __builtin_amdgcn_s_sleep(127);
        } else {
          __builtin_amdgcn_s_sleep(32);
        }
        __syncthreads();  // all waves done reading cntS before next poll-write
      }
      if (t == 0) cntS[0] = ldUi(&p.lat[r]);
      __syncthreads();
    }
    int tok = cntS[0];
    if (t < D) hS[0][t] = p.emb[tok * D + t] + p.pos[r * D + t];
    __syncthreads();
    lnorm(p.ln1_s, p.ln1_b, hS[0], xnS, redS);
    qkvPub<true>(p, 0, r, split, xnS, qS[0]);  // done-chain = real ordering
    for (int l = 0; l < NLAYER; ++l) {
      if (leadRow && t == 0) stUi(p.prog, l);  // wave leader publishes layer
      attnProjFFN(p, r, l, hS[0], qS[0], oS, xnS, fS, padS, redS);
      if (l < NLAYER - 1) {
        lnorm(p.ln1_s + (l+1)*D, p.ln1_b + (l+1)*D, hS[0], xnS, redS);
        qkvPub<true>(p, l + 1, r, split, xnS, qS[0]);
      } else {
        headRow<true>(p, r, hS[0], xnS, redS, padS, oS);
      }
    }
    if (hk >= 0 && t == 0) {
      int best = 0; float bv = oS[0];
      for (int v = 1; v < BOSX; ++v)
        if (oS[v] > bv) { bv = oS[v]; best = v; }
      stUi(&p.lat[r + 1], best);
      asm volatile("s_waitcnt vmcnt(0)" ::: "memory");
      stUi(p.heals_done, hk + 1);
    }
  }

  barFull(cnt, b);

  // ================= tokens out =================
  {
    int gid = wg * NT + t;
    if (gid < L) p.out_tok[gid] = (float)ldUi(&p.lat[gid + 1]);
  }
}

extern "C" void kernel_launch(void* const* d_in, const int* in_sizes, int n_in,
                              void* d_out, int out_size, void* d_ws, size_t ws_size,
                              hipStream_t stream) {
  P prm;
  prm.tokens = (const int*)d_in[0];
  prm.emb    = (const float*)d_in[1];
  prm.pos    = (const float*)d_in[2];
  prm.ln1_s  = (const float*)d_in[3];
  prm.ln1_b  = (const float*)d_in[4];
  prm.wqkv   = (const float*)d_in[5];
  prm.bqkv   = (const float*)d_in[6];
  prm.wo     = (const float*)d_in[7];
  prm.bo     = (const float*)d_in[8];
  prm.ln2_s  = (const float*)d_in[9];
  prm.ln2_b  = (const float*)d_in[10];
  prm.w1     = (const float*)d_in[11];
  prm.b1     = (const float*)d_in[12];
  prm.w2     = (const float*)d_in[13];
  prm.b2     = (const float*)d_in[14];
  prm.lnf_s  = (const float*)d_in[15];
  prm.lnf_b  = (const float*)d_in[16];
  prm.hw     = (const float*)d_in[17];
  prm.hb     = (const float*)d_in[18];

  float* ws = (float*)d_ws;
  prm.kc   = ws;                            // NLAYER*L*D
  prm.vc   = prm.kc + (size_t)NLAYER*L*D;   // NLAYER*L*D
  prm.ll_  = prm.vc + (size_t)NLAYER*L*D;   // L
  prm.lat        = (int*)(prm.ll_ + L);     // 1025 (pad 1032)
  prm.heal_row   = prm.lat + 1032;          // 32 ([31] = count)
  prm.barc       = prm.heal_row + 32;       // 64
  prm.done       = prm.barc + 64;           // NLAYER*L
  prm.heals_done = prm.done + NLAYER * L;   // 16 (prog = +8, zeroed by kInit)
  prm.prog       = prm.heals_done + 8;

  prm.logits  = (float*)d_out;              // L*V
  prm.out_tok = prm.logits + L * V;         // L

  kInit<<<64, 256, 0, stream>>>(prm.tokens, prm.lat, prm.barc, prm.done, prm.heals_done);

  void* args[] = { &prm };
  (void)hipLaunchCooperativeKernel((const void*)kMega, dim3(NWG), dim3(NT), args, 0, stream);
}

// Round 17
// 17092.624 us; speedup vs baseline: 1.8630x; 1.0246x over previous
//
#include <hip/hip_runtime.h>
#include <math.h>

#define D 128
#define NLAYER 16
#define V 17
#define L 1024
#define BOSX 16
#define NWG 256
#define NT 512

struct P {
  const int* tokens;
  const float *emb, *pos, *ln1_s, *ln1_b, *wqkv, *bqkv, *wo, *bo;
  const float *ln2_s, *ln2_b, *w1, *b1, *w2, *b2, *lnf_s, *lnf_b, *hw, *hb;
  float *kc, *vc, *ll_;
  int *lat, *heal_row, *barc, *done, *heals_done, *prog;
  float *logits, *out_tok;
};

// ---- uncached (coherence-point) accessors ----
__device__ __forceinline__ void stUf(float* p, float v) {
  __hip_atomic_store(p, v, __ATOMIC_RELAXED, __HIP_MEMORY_SCOPE_SYSTEM);
}
__device__ __forceinline__ int ldUi(const int* p) {
  return __hip_atomic_load((int*)p, __ATOMIC_RELAXED, __HIP_MEMORY_SCOPE_SYSTEM);
}
__device__ __forceinline__ void stUi(int* p, int v) {
  __hip_atomic_store(p, v, __ATOMIC_RELAXED, __HIP_MEMORY_SCOPE_SYSTEM);
}

// ---- light barrier: vmcnt drain + counter, NO cache maintenance.
// Safe whenever all cross-WG data moved via uncached stores (demand-fetch reads).
__device__ __forceinline__ void barLight(int* cnt, int& b) {
  asm volatile("s_waitcnt vmcnt(0)" ::: "memory");
  __syncthreads();
  if (threadIdx.x == 0) {
    __hip_atomic_fetch_add(cnt, 1, __ATOMIC_RELAXED, __HIP_MEMORY_SCOPE_AGENT);
    int tgt = (b + 1) * NWG;
    while (__hip_atomic_load(cnt, __ATOMIC_RELAXED, __HIP_MEMORY_SCOPE_AGENT) < tgt)
      __builtin_amdgcn_s_sleep(4);
  }
  b += 1;
  __syncthreads();
}

// ---- full barrier: wb/inv fence, relaxed spin (post-sort transition only) ----
__device__ __forceinline__ void barFull(int* cnt, int& b) {
  asm volatile("s_waitcnt vmcnt(0)" ::: "memory");
  __syncthreads();
  if (threadIdx.x == 0) {
    __threadfence();
    __hip_atomic_fetch_add(cnt, 1, __ATOMIC_RELAXED, __HIP_MEMORY_SCOPE_AGENT);
    int tgt = (b + 1) * NWG;
    while (__hip_atomic_load(cnt, __ATOMIC_RELAXED, __HIP_MEMORY_SCOPE_AGENT) < tgt)
      __builtin_amdgcn_s_sleep(8);
    __threadfence();
  }
  b += 1;
  __syncthreads();
}

__device__ __forceinline__ float geluf(float a) {
  float cgv = 0.7978845608028654f * (a + 0.044715f * a * a * a);
  cgv = fminf(fmaxf(cgv, -15.f), 15.f);
  float e = __expf(2.f * cgv);
  return 0.5f * a * (1.f + (e - 1.f) / (e + 1.f));
}

// Fused single-pass LayerNorm (sum+sumsq in one cascade); 2 barriers.
__device__ void lnorm(const float* __restrict__ s, const float* __restrict__ b,
                      const float* in, float* out, float* red) {
  int t = threadIdx.x;
  float v = (t < D) ? in[t] : 0.f;
  float sm = v, sq = v * v;
#pragma unroll
  for (int o = 32; o; o >>= 1) {
    sm += __shfl_xor(sm, o, 64);
    sq += __shfl_xor(sq, o, 64);
  }
  if (t < D && (t & 63) == 0) { red[(t >> 6) * 2] = sm; red[(t >> 6) * 2 + 1] = sq; }
  __syncthreads();
  float mean = (red[0] + red[2]) * (1.f / 128.f);
  float ex2  = (red[1] + red[3]) * (1.f / 128.f);
  float rstd = rsqrtf(ex2 - mean * mean + 1e-5f);
  if (t < D) out[t] = (v - mean) * rstd * s[t] + b[t];
  __syncthreads();
}

// QKV for one row: q->LDS, K/V->global uncached (always); done-chain when HEAL.
template <bool HEAL>
__device__ void qkvPub(const P& p, int l, int row, int split, const float* x, float* qrow) {
  int t = threadIdx.x;
  if (t < 384) {
    const float* w = p.wqkv + (size_t)l * D * 384 + t;
    float a = 0.f;
#pragma unroll 16
    for (int d = 0; d < D; ++d) a += x[d] * w[d * 384];
    a += p.bqkv[l * 384 + t];
    float* kcl = p.kc + (size_t)l * L * D + (size_t)row * D;
    float* vcl = p.vc + (size_t)l * L * D + (size_t)row * D;
    if (t < 128) qrow[t] = a;
    else if (t < 256) stUf(&kcl[t - 128], a);
    else              stUf(&vcl[t - 256], a);
  }
  if (HEAL) {
    asm volatile("s_waitcnt vmcnt(0)" ::: "memory");
    __syncthreads();
    if (t == 0) {
      int* dl = p.done + l * L;
      if (row - 1 >= split)
        while (ldUi(&dl[row - 1]) < 1) __builtin_amdgcn_s_sleep(1);
      stUi(&dl[row], 1);
    }
    __syncthreads();
  } else {
    __syncthreads();
  }
}

// attention(l)+proj+res+LN2+FF1+FF2+res for one row (h in LDS). K/V reads cached.
__device__ void attnProjFFN(const P& p, int row, int l,
                            float* hrow, const float* qrow,
                            float* oS, float* xnS, float* fS, float* padS, float* redS) {
  int t = threadIdx.x;
  const float* kcl = p.kc + (size_t)l * L * D;
  const float* vcl = p.vc + (size_t)l * L * D;
  int head = t >> 5, lane = t & 31;
  const float* qh = qrow + head * 8;
  float q0=qh[0],q1=qh[1],q2=qh[2],q3=qh[3],q4=qh[4],q5=qh[5],q6=qh[6],q7=qh[7];
  float sum = 0.f, a0=0,a1=0,a2=0,a3=0,a4=0,a5=0,a6=0,a7=0;
#pragma unroll 4
  for (int key = lane; key <= row; key += 32) {
    const float4* kp = (const float4*)(kcl + (size_t)key * D + head * 8);
    float4 k0 = kp[0], k1 = kp[1];
    float sc = q0*k0.x+q1*k0.y+q2*k0.z+q3*k0.w+q4*k1.x+q5*k1.y+q6*k1.z+q7*k1.w;
    float pr = __expf(sc * 0.35355339059327376f);
    const float4* vp = (const float4*)(vcl + (size_t)key * D + head * 8);
    float4 v0 = vp[0], v1 = vp[1];
    sum += pr;
    a0+=pr*v0.x; a1+=pr*v0.y; a2+=pr*v0.z; a3+=pr*v0.w;
    a4+=pr*v1.x; a5+=pr*v1.y; a6+=pr*v1.z; a7+=pr*v1.w;
  }
#pragma unroll
  for (int o = 1; o < 32; o <<= 1) {
    sum += __shfl_xor(sum, o, 32);
    a0 += __shfl_xor(a0, o, 32); a1 += __shfl_xor(a1, o, 32);
    a2 += __shfl_xor(a2, o, 32); a3 += __shfl_xor(a3, o, 32);
    a4 += __shfl_xor(a4, o, 32); a5 += __shfl_xor(a5, o, 32);
    a6 += __shfl_xor(a6, o, 32); a7 += __shfl_xor(a7, o, 32);
  }
  if (lane == 0) {
    float inv = 1.f / sum;
    oS[head*8+0]=a0*inv; oS[head*8+1]=a1*inv; oS[head*8+2]=a2*inv; oS[head*8+3]=a3*inv;
    oS[head*8+4]=a4*inv; oS[head*8+5]=a5*inv; oS[head*8+6]=a6*inv; oS[head*8+7]=a7*inv;
  }
  __syncthreads();
  // ---- proj: 4 segs x 32 deep ----
  {
    int col = t & 127, seg = t >> 7;
    const float* wp = p.wo + (size_t)l * D * D + col;
    float acc = 0.f;
    int d0 = seg * 32;
#pragma unroll 8
    for (int d = d0; d < d0 + 32; ++d) acc += oS[d] * wp[d * D];
    padS[t] = acc;
  }
  __syncthreads();
  if (t < D) hrow[t] += padS[t] + padS[t+128] + padS[t+256] + padS[t+384] + p.bo[l * D + t];
  __syncthreads();
  lnorm(p.ln2_s + l * D, p.ln2_b + l * D, hrow, xnS, redS);
  // ---- FF1: col per thread ----
  {
    const float* w1p = p.w1 + (size_t)l * D * 512 + t;
    float acc = 0.f;
#pragma unroll 16
    for (int d = 0; d < D; ++d) acc += xnS[d] * w1p[d * 512];
    fS[t] = geluf(acc + p.b1[l * 512 + t]);
  }
  __syncthreads();
  // ---- FF2: 4 segs x 128 deep ----
  {
    int col = t & 127, seg = t >> 7;
    const float* w2p = p.w2 + (size_t)l * 512 * D + col;
    float acc = 0.f;
    int d0 = seg * 128;
#pragma unroll 16
    for (int d = d0; d < d0 + 128; ++d) acc += fS[d] * w2p[d * D];
    padS[t] = acc;
  }
  __syncthreads();
  if (t < D) hrow[t] += padS[t] + padS[t+128] + padS[t+256] + padS[t+384] + p.b2[l * D + t];
  __syncthreads();
}

// LNf + head for one row; logits -> global uncached (+ oS LDS for argmax)
__device__ void headRow(const P& p, int row, float* hrow,
                        float* xnS, float* redS, float* padS, float* oS) {
  lnorm(p.lnf_s, p.lnf_b, hrow, xnS, redS);
  int t = threadIdx.x;
  if (t < V * 8) {
    int col = t >> 3, seg = t & 7;
    float acc = 0.f;
    int d0 = seg * 16;
#pragma unroll
    for (int d = d0; d < d0 + 16; ++d) acc += xnS[d] * p.hw[d * V + col];
    padS[t] = acc;
  }
  __syncthreads();
  if (t < V) {
    float a = padS[t*8]+padS[t*8+1]+padS[t*8+2]+padS[t*8+3]
            + padS[t*8+4]+padS[t*8+5]+padS[t*8+6]+padS[t*8+7] + p.hb[t];
    oS[t] = a;
    stUf(&p.logits[row * V + t], a);
  }
  __syncthreads();
}

// ---- init: lat + flags, all uncached ----
__global__ void kInit(const int* __restrict__ tokens, int* __restrict__ lat,
                      int* __restrict__ barc, int* __restrict__ done,
                      int* __restrict__ hd) {
  int i = blockIdx.x * blockDim.x + threadIdx.x;
  if (i == 0) stUi(lat, BOSX);
  if (i < L) stUi(lat + i + 1, tokens[i]);
  if (i < 64) stUi(barc + i, 0);
  if (i < 16) stUi(hd + i, 0);   // heals_done[0..7], prog at hd+8
  if (i < NLAYER * L) stUi(done + i, 0);
}

__global__ void __launch_bounds__(NT, 1) kMega(P p) {
  __shared__ float hS[4][D];
  __shared__ float qS[4][D];
  __shared__ float xnS[D];
  __shared__ float oS[D];
  __shared__ float fS[512];
  __shared__ float padS[512];
  __shared__ float redS[16];
  __shared__ float sortS[L];
  __shared__ int cntS[NT + 1];
  int wg = blockIdx.x, t = threadIdx.x;
  int b = 0;
  int* cnt = p.barc;

  // ===== PHASE A: full pass, 4 rows/WG. All cross-WG publishes uncached, =====
  // ===== so per-layer barriers are fence-free (dispatch boundary inv'ed). ====
  for (int i = 0; i < 4; ++i) {
    int row = wg + i * NWG;
    int tok = p.lat[row];
    if (t < D) hS[i][t] = p.emb[tok * D + t] + p.pos[row * D + t];
    __syncthreads();
    lnorm(p.ln1_s, p.ln1_b, hS[i], xnS, redS);
    qkvPub<false>(p, 0, row, 0, xnS, qS[i]);
  }
  barLight(cnt, b);
  for (int l = 0; l < NLAYER; ++l) {
    for (int i = 0; i < 4; ++i) {
      int row = wg + i * NWG;
      attnProjFFN(p, row, l, hS[i], qS[i], oS, xnS, fS, padS, redS);
      if (l < NLAYER - 1) {
        lnorm(p.ln1_s + (l+1)*D, p.ln1_b + (l+1)*D, hS[i], xnS, redS);
        qkvPub<false>(p, l + 1, row, 0, xnS, qS[i]);
      } else {
        headRow(p, row, hS[i], xnS, redS, padS, oS);
      }
    }
    barLight(cnt, b);
  }

  // ================= log-likelihoods (uncached publish) =================
  {
    int gid = wg * NT + t;
    if (gid < L) {
      float r[V];
#pragma unroll
      for (int v = 0; v < V; ++v) r[v] = p.logits[gid * V + v];
      float m = r[0];
#pragma unroll
      for (int v = 1; v < V; ++v) m = fmaxf(m, r[v]);
      float s = 0.f;
#pragma unroll
      for (int v = 0; v < V; ++v) s += expf(r[v] - m);
      stUf(&p.ll_[gid], r[p.lat[gid + 1]] - (m + logf(s)));
    }
  }
  barLight(cnt, b);

  // ================= sort + quantile + heal list (WG 0) =================
  if (wg == 0) {
    for (int i = t; i < L; i += NT) sortS[i] = p.ll_[i];
    __syncthreads();
    for (int ksz = 2; ksz <= L; ksz <<= 1) {
      for (int j = ksz >> 1; j; j >>= 1) {
        for (int i = t; i < L; i += NT) {
          int l2 = i ^ j;
          if (l2 > i) {
            bool up = ((i & ksz) == 0);
            float a = sortS[i], bb = sortS[l2];
            if ((a > bb) == up) { sortS[i] = bb; sortS[l2] = a; }
          }
        }
        __syncthreads();
      }
    }
    if (t == 0) {
      double frac = 0.03 * 1023.0 - 30.0;  // 0.69
      redS[0] = (float)((double)sortS[30] + frac * ((double)sortS[31] - (double)sortS[30]));
    }
    __syncthreads();
    float val = redS[0];
    float lv0 = p.ll_[t * 2], lv1 = p.ll_[t * 2 + 1];
    int loc[2], cc = 0;
    if (lv0 < val) loc[cc++] = t * 2;
    if (lv1 < val) loc[cc++] = t * 2 + 1;
    cntS[t] = cc;
    __syncthreads();
    if (t == 0) {
      int run = 0;
      for (int i = 0; i < NT; ++i) { int c2 = cntS[i]; cntS[i] = run; run += c2; }
      cntS[NT] = run;
    }
    __syncthreads();
    int base = cntS[t];
    for (int j = 0; j < cc; ++j)
      if (base + j < 31) p.heal_row[base + j] = loc[j];
    __syncthreads();
    if (t == 0) {
      int c = cntS[NT]; if (c > 31) c = 31;
      p.heal_row[31] = c;
      stUi(p.heals_done, 1);
      if (c > 0) {
        int r0 = p.heal_row[0];
        int best = 0; float bv = p.logits[r0 * V];
        for (int v = 1; v < BOSX; ++v) {
          float x = p.logits[r0 * V + v];
          if (x > bv) { bv = x; best = v; }
        }
        stUi(&p.lat[r0 + 1], best);
      }
    }
  }
  barFull(cnt, b);  // REQUIRED inv: drops phase-A-cached K/V lines of rows >= split

  // ===== HEAL: continuous wavefront. Non-lead rows flow on the done-chain; =====
  int c = p.heal_row[31];
  int split = (c > 0) ? (p.heal_row[0] + 1) : L;
  for (int r = split + wg; r < L; r += NWG) {
    int nh = 0, hk = -1;
    bool leadRow = false;  // r == heal_row[j]+1 for some j: lat[r] changes
    for (int j = 0; j < c; ++j) {
      nh += (p.heal_row[j] < r) ? 1 : 0;
      if (j >= 1 && p.heal_row[j] == r) hk = j;
      if (p.heal_row[j] == r - 1) leadRow = true;
    }
    int gate = leadRow ? nh : (nh - 2);
    // --- wait: warm L2 + distance-aware poll backoff ---
    {
      int pfi = (wg * 11) % 224;
      for (;;) {
        if (t == 0) { cntS[0] = ldUi(p.heals_done); cntS[1] = ldUi(p.prog); }
        __syncthreads();
        int hd = cntS[0];
        int pl = (cntS[1] + 1) & 15;
        if (hd >= gate) break;
        int dist = gate - hd;
        if (leadRow && dist == 1) {
          __builtin_amdgcn_s_sleep(1);
          __syncthreads();
          continue;
        }
        int R = p.heal_row[hd - 1];  // rows <= R are final at every layer
        float sink = 0.f;
#pragma unroll
        for (int j2 = 0; j2 < 6; ++j2) {
          int ch = pfi + j2; if (ch >= 224) ch -= 224;
          const float* basep = nullptr;
          if (ch < 24)      basep = p.wqkv + (size_t)pl * D * 384 + ch * 2048;
          else if (ch < 32) basep = p.wo   + (size_t)pl * D * D   + (ch - 24) * 2048;
          else if (ch < 64) basep = p.w1   + (size_t)pl * D * 512 + (ch - 32) * 2048;
          else if (ch < 96) basep = p.w2   + (size_t)pl * 512 * D + (ch - 64) * 2048;
          else {
            int kvch = ch - 96;          // 0..127: 64 K-blocks + 64 V-blocks
            int blk = (kvch & 63) * 16;  // 16 rows x 128 floats
            if (blk + 15 <= R)
              basep = (kvch < 64 ? p.kc : p.vc) + (size_t)pl * L * D + (size_t)blk * D;
          }
          if (basep) {
            float4 v = *(const float4*)(basep + t * 4);
            sink += v.x + v.y + v.z + v.w;
          }
        }
        asm volatile("" :: "v"(sink));  // keep warm loads live (no DCE)
        pfi += 6; if (pfi >= 224) pfi -= 224;
        if (dist >= 4) {
          __builtin_amdgcn_s_sleep(127); __builtin_amdgcn_s_sleep(127);
          __builtin_amdgcn_s_sleep(127); __builtin_amdgcn_s_sleep(127);
        } else if (dist >= 2) {
          __builtin_amdgcn_s_sleep(127);
        } else {
          __builtin_amdgcn_s_sleep(32);
        }
        __syncthreads();
      }
      if (t == 0) cntS[0] = ldUi(&p.lat[r]);
      __syncthreads();
    }
    int tok = cntS[0];
    if (t < D) hS[0][t] = p.emb[tok * D + t] + p.pos[r * D + t];
    __syncthreads();
    lnorm(p.ln1_s, p.ln1_b, hS[0], xnS, redS);
    qkvPub<true>(p, 0, r, split, xnS, qS[0]);
    for (int l = 0; l < NLAYER; ++l) {
      if (leadRow && t == 0) stUi(p.prog, l);
      attnProjFFN(p, r, l, hS[0], qS[0], oS, xnS, fS, padS, redS);
      if (l < NLAYER - 1) {
        lnorm(p.ln1_s + (l+1)*D, p.ln1_b + (l+1)*D, hS[0], xnS, redS);
        qkvPub<true>(p, l + 1, r, split, xnS, qS[0]);
      } else {
        headRow(p, r, hS[0], xnS, redS, padS, oS);
      }
    }
    if (hk >= 0 && t == 0) {
      int best = 0; float bv = oS[0];
      for (int v = 1; v < BOSX; ++v)
        if (oS[v] > bv) { bv = oS[v]; best = v; }
      stUi(&p.lat[r + 1], best);
      asm volatile("s_waitcnt vmcnt(0)" ::: "memory");
      stUi(p.heals_done, hk + 1);
    }
  }

  barLight(cnt, b);

  // ================= tokens out =================
  {
    int gid = wg * NT + t;
    if (gid < L) p.out_tok[gid] = (float)ldUi(&p.lat[gid + 1]);
  }
}

extern "C" void kernel_launch(void* const* d_in, const int* in_sizes, int n_in,
                              void* d_out, int out_size, void* d_ws, size_t ws_size,
                              hipStream_t stream) {
  P prm;
  prm.tokens = (const int*)d_in[0];
  prm.emb    = (const float*)d_in[1];
  prm.pos    = (const float*)d_in[2];
  prm.ln1_s  = (const float*)d_in[3];
  prm.ln1_b  = (const float*)d_in[4];
  prm.wqkv   = (const float*)d_in[5];
  prm.bqkv   = (const float*)d_in[6];
  prm.wo     = (const float*)d_in[7];
  prm.bo     = (const float*)d_in[8];
  prm.ln2_s  = (const float*)d_in[9];
  prm.ln2_b  = (const float*)d_in[10];
  prm.w1     = (const float*)d_in[11];
  prm.b1     = (const float*)d_in[12];
  prm.w2     = (const float*)d_in[13];
  prm.b2     = (const float*)d_in[14];
  prm.lnf_s  = (const float*)d_in[15];
  prm.lnf_b  = (const float*)d_in[16];
  prm.hw     = (const float*)d_in[17];
  prm.hb     = (const float*)d_in[18];

  float* ws = (float*)d_ws;
  prm.kc   = ws;                            // NLAYER*L*D
  prm.vc   = prm.kc + (size_t)NLAYER*L*D;   // NLAYER*L*D
  prm.ll_  = prm.vc + (size_t)NLAYER*L*D;   // L
  prm.lat        = (int*)(prm.ll_ + L);     // 1025 (pad 1032)
  prm.heal_row   = prm.lat + 1032;          // 32 ([31] = count)
  prm.barc       = prm.heal_row + 32;       // 64
  prm.done       = prm.barc + 64;           // NLAYER*L
  prm.heals_done = prm.done + NLAYER * L;   // 16 (prog = +8, zeroed by kInit)
  prm.prog       = prm.heals_done + 8;

  prm.logits  = (float*)d_out;              // L*V
  prm.out_tok = prm.logits + L * V;         // L

  kInit<<<64, 256, 0, stream>>>(prm.tokens, prm.lat, prm.barc, prm.done, prm.heals_done);

  void* args[] = { &prm };
  (void)hipLaunchCooperativeKernel((const void*)kMega, dim3(NWG), dim3(NT), args, 0, stream);
}